// Round 5
// baseline (135.555 us; speedup 1.0000x reference)
//
#include <hip/hip_runtime.h>

#define NV 1084
#define NB 8   // batches per verts block

// ws layout (floats):
//  [0, B*192)            A_rel [B][16][12]
//  next B*45             euler_pose [B][45]
//  next 4*1392           Mpart[4]: each = M[21][16][4] (1344) + jt[48]

__device__ inline void rodrigues9(float x, float y, float z, float R[9]) {
    float n2 = x * x + y * y + z * z + 1e-8f;
    float angle = sqrtf(n2);
    float inv = 1.0f / angle;
    float ax = x * inv, ay = y * inv, az = z * inv;
    float c = cosf(angle), s = sinf(angle);
    float C = 1.0f - c;
    R[0] = 1.0f - C * (ay * ay + az * az);
    R[1] = -s * az + C * ax * ay;
    R[2] = s * ay + C * ax * az;
    R[3] = s * az + C * ax * ay;
    R[4] = 1.0f - C * (ax * ax + az * az);
    R[5] = -s * ax + C * ay * az;
    R[6] = -s * ay + C * ax * az;
    R[7] = s * ax + C * ay * az;
    R[8] = 1.0f - C * (ax * ax + ay * ay);
}

// K1: blocks [0, nEuler): euler_pose. blocks [nEuler, nEuler+4): precompute
// partial M/jt over a quarter of the vertices (271 each; 4*271 = 1084). No atomics.
__global__ __launch_bounds__(384) void prep_kernel(
    const float* __restrict__ theta, const float* __restrict__ hc,
    const float* __restrict__ hm, const float* __restrict__ vt,
    const float* __restrict__ jreg, const float* __restrict__ wts,
    float* __restrict__ euler, float* __restrict__ Mpart, int B) {
    int blk = blockIdx.x;
    int t = threadIdx.x;
    int nEuler = (B * 45 + 383) / 384;
    if (blk < nEuler) {
        int i = blk * 384 + t;
        if (i < B * 45) {
            int b = i / 45, col = i - b * 45;
            const float* th = theta + (size_t)b * 45;
            float acc = hm[col];
#pragma unroll
            for (int k = 0; k < 45; ++k) acc += th[k] * hc[k * 45 + col];
            euler[i] = acc;
        }
    } else {
        int p = blk - nEuler;           // 0..3
        int v0 = p * 271, v1 = v0 + 271;
        float* mp = Mpart + (size_t)p * 1392;
        if (t < 336) {
            int j = t >> 4, k = t & 15;
            float m0 = 0.f, m1 = 0.f, m2 = 0.f, s = 0.f;
            for (int v = v0; v < v1; ++v) {
                float jw = jreg[v * 21 + j] * wts[v * 16 + k];
                m0 += jw * vt[v * 3 + 0];
                m1 += jw * vt[v * 3 + 1];
                m2 += jw * vt[v * 3 + 2];
                s += jw;
            }
            mp[t * 4 + 0] = m0;
            mp[t * 4 + 1] = m1;
            mp[t * 4 + 2] = m2;
            mp[t * 4 + 3] = s;
        } else {                        // t in [336, 384): 48 jt entries
            int o = t - 336;
            int j = o / 3, c = o - j * 3;   // j < 16
            float acc = 0.f;
            for (int v = v0; v < v1; ++v) acc += vt[v * 3 + c] * jreg[v * 21 + j];
            mp[1344 + o] = acc;
        }
    }
}

// K2: FK split per chain: thread = (batch, role r in 0..4). Role r computes chain r
// (joints 3r+1..3r+3); every role redundantly computes the root A0; role 0 writes it.
__global__ __launch_bounds__(256) void fk_kernel(
    const float* __restrict__ wrist, const float* __restrict__ euler,
    const float* __restrict__ Mpart, float* __restrict__ wsA, int total) {
    __shared__ float sj[48];
    int t = threadIdx.x;
    if (t < 48) {
        sj[t] = Mpart[1344 + t] + Mpart[1392 + 1344 + t] +
                Mpart[2 * 1392 + 1344 + t] + Mpart[3 * 1392 + 1344 + t];
    }
    __syncthreads();
    int idx = blockIdx.x * 256 + t;
    if (idx >= total) return;  // total = B*5
    int b = idx / 5, r = idx - b * 5;

    float R[9];
    rodrigues9(wrist[b * 3 + 0], wrist[b * 3 + 1], wrist[b * 3 + 2], R);
    float J0x = sj[0], J0y = sj[1], J0z = sj[2];
    float Ap[12];
    Ap[0] = R[0]; Ap[1] = R[1]; Ap[2] = R[2]; Ap[3] = J0x;
    Ap[4] = R[3]; Ap[5] = R[4]; Ap[6] = R[5]; Ap[7] = J0y;
    Ap[8] = R[6]; Ap[9] = R[7]; Ap[10] = R[8]; Ap[11] = J0z;
    float* out = wsA + (size_t)b * 192;
    if (r == 0) {
#pragma unroll
        for (int row = 0; row < 3; ++row) {
            out[row * 4 + 0] = Ap[row * 4 + 0];
            out[row * 4 + 1] = Ap[row * 4 + 1];
            out[row * 4 + 2] = Ap[row * 4 + 2];
            out[row * 4 + 3] = Ap[row * 4 + 3] -
                (Ap[row * 4 + 0] * J0x + Ap[row * 4 + 1] * J0y + Ap[row * 4 + 2] * J0z);
        }
    }
    float px = J0x, py = J0y, pz = J0z;
    const float* eb = euler + (size_t)b * 45 + 9 * r;
#pragma unroll
    for (int s = 0; s < 3; ++s) {
        int i = r * 3 + s + 1;
        rodrigues9(eb[3 * s + 0], eb[3 * s + 1], eb[3 * s + 2], R);
        float jx = sj[i * 3 + 0], jy = sj[i * 3 + 1], jz = sj[i * 3 + 2];
        float tx = jx - px, ty = jy - py, tz = jz - pz;
        float An[12];
#pragma unroll
        for (int row = 0; row < 3; ++row) {
            An[row * 4 + 0] = Ap[row * 4 + 0] * R[0] + Ap[row * 4 + 1] * R[3] + Ap[row * 4 + 2] * R[6];
            An[row * 4 + 1] = Ap[row * 4 + 0] * R[1] + Ap[row * 4 + 1] * R[4] + Ap[row * 4 + 2] * R[7];
            An[row * 4 + 2] = Ap[row * 4 + 0] * R[2] + Ap[row * 4 + 1] * R[5] + Ap[row * 4 + 2] * R[8];
            An[row * 4 + 3] = Ap[row * 4 + 3] + Ap[row * 4 + 0] * tx + Ap[row * 4 + 1] * ty + Ap[row * 4 + 2] * tz;
        }
        float* oi = out + i * 12;
#pragma unroll
        for (int row = 0; row < 3; ++row) {
            oi[row * 4 + 0] = An[row * 4 + 0];
            oi[row * 4 + 1] = An[row * 4 + 1];
            oi[row * 4 + 2] = An[row * 4 + 2];
            oi[row * 4 + 3] = An[row * 4 + 3] -
                (An[row * 4 + 0] * jx + An[row * 4 + 1] * jy + An[row * 4 + 2] * jz);
        }
#pragma unroll
        for (int q = 0; q < 12; ++q) Ap[q] = An[q];
        px = jx; py = jy; pz = jz;
    }
}

#define BLEND16(T, w)                                                     \
    {                                                                     \
        _Pragma("unroll")                                                 \
        for (int q = 0; q < 12; ++q) T[q] = w[0] * A[q];                  \
        _Pragma("unroll")                                                 \
        for (int k = 1; k < 16; ++k) {                                    \
            float wk = w[k];                                              \
            _Pragma("unroll")                                             \
            for (int q = 0; q < 12; ++q) T[q] += wk * A[k * 12 + q];      \
        }                                                                 \
    }

__device__ inline void load_w16(const float* __restrict__ wts, int v, float* w) {
    const float4* wp = (const float4*)&wts[v * 16];
    float4 q0 = wp[0], q1 = wp[1], q2 = wp[2], q3 = wp[3];
    w[0] = q0.x; w[1] = q0.y; w[2] = q0.z; w[3] = q0.w;
    w[4] = q1.x; w[5] = q1.y; w[6] = q1.z; w[7] = q1.w;
    w[8] = q2.x; w[9] = q2.y; w[10] = q2.z; w[11] = q2.w;
    w[12] = q3.x; w[13] = q3.y; w[14] = q3.z; w[15] = q3.w;
}

// K3: grid = (B/NB)*3. chunk 0/1: 512 verts each (VPT=2). chunk 2: 60-vert tail + joints.
// A is wave-uniform -> SGPR s_loads; no LDS.
__global__ __launch_bounds__(256) void verts_joints_kernel(
    const float* __restrict__ wsA, const float* __restrict__ Mpart,
    const float* __restrict__ wts, const float* __restrict__ vtpl,
    float* __restrict__ verts, float* __restrict__ jout) {
    int bid = blockIdx.x;
    int bg = bid / 3, chunk = bid - bg * 3;
    int t = threadIdx.x;
    int b0 = bg * NB;

    if (chunk < 2) {
        int v0 = chunk * 512 + t;       // v0 and v0+256, both < 1024 <= NV
        int v1 = v0 + 256;
        float w0[16], w1[16];
        load_w16(wts, v0, w0);
        load_w16(wts, v1, w1);
        float vx0 = vtpl[v0 * 3 + 0], vy0 = vtpl[v0 * 3 + 1], vz0 = vtpl[v0 * 3 + 2];
        float vx1 = vtpl[v1 * 3 + 0], vy1 = vtpl[v1 * 3 + 1], vz1 = vtpl[v1 * 3 + 2];
#pragma unroll 1
        for (int bb = 0; bb < NB; ++bb) {
            const float* A = wsA + (size_t)(b0 + bb) * 192;  // uniform -> SGPR
            float T0[12], T1[12];
            BLEND16(T0, w0)
            BLEND16(T1, w1)
            float* ob = verts + (size_t)(b0 + bb) * (NV * 3);
            float ox = T0[0] * vx0 + T0[1] * vy0 + T0[2] * vz0 + T0[3];
            float oy = T0[4] * vx0 + T0[5] * vy0 + T0[6] * vz0 + T0[7];
            float oz = T0[8] * vx0 + T0[9] * vy0 + T0[10] * vz0 + T0[11];
            ob[v0 * 3 + 0] = ox; ob[v0 * 3 + 1] = oy; ob[v0 * 3 + 2] = oz;
            ox = T1[0] * vx1 + T1[1] * vy1 + T1[2] * vz1 + T1[3];
            oy = T1[4] * vx1 + T1[5] * vy1 + T1[6] * vz1 + T1[7];
            oz = T1[8] * vx1 + T1[9] * vy1 + T1[10] * vz1 + T1[11];
            ob[v1 * 3 + 0] = ox; ob[v1 * 3 + 1] = oy; ob[v1 * 3 + 2] = oz;
        }
    } else {
        // tail verts 1024..1083 (60 lanes) + joints for these NB batches
        int v = 1024 + t;
        bool valid = (v < NV);
        float w[16];
        float vx = 0.f, vy = 0.f, vz = 0.f;
        if (valid) {
            load_w16(wts, v, w);
            vx = vtpl[v * 3 + 0]; vy = vtpl[v * 3 + 1]; vz = vtpl[v * 3 + 2];
        } else {
#pragma unroll
            for (int q = 0; q < 16; ++q) w[q] = 0.f;
        }
#pragma unroll 1
        for (int bb = 0; bb < NB; ++bb) {
            const float* A = wsA + (size_t)(b0 + bb) * 192;
            float T[12];
            BLEND16(T, w)
            if (valid) {
                float ox = T[0] * vx + T[1] * vy + T[2] * vz + T[3];
                float oy = T[4] * vx + T[5] * vy + T[6] * vz + T[7];
                float oz = T[8] * vx + T[9] * vy + T[10] * vz + T[11];
                float* o = verts + (size_t)(b0 + bb) * (NV * 3) + v * 3;
                o[0] = ox; o[1] = oy; o[2] = oz;
            }
        }
        // joints: jout[b, j, c] = sum_k sum_d M[j][k][d] * A[b][k][c*4+d]
        // M reduced inline from the 4 partials.
        for (int o = t; o < NB * 63; o += 256) {
            int bl = o / 63;
            int rem = o - bl * 63;
            int j = rem / 3;
            int c = rem - j * 3;
            const float* A = wsA + (size_t)(b0 + bl) * 192 + c * 4;
            const float* M0 = Mpart + j * 64;
            const float* M1 = M0 + 1392;
            const float* M2 = M1 + 1392;
            const float* M3 = M2 + 1392;
            float acc = 0.f;
#pragma unroll
            for (int k = 0; k < 16; ++k) {
                float4 a = *(const float4*)&A[k * 12];
                float4 ma = *(const float4*)&M0[k * 4];
                float4 mb = *(const float4*)&M1[k * 4];
                float4 mc = *(const float4*)&M2[k * 4];
                float4 md = *(const float4*)&M3[k * 4];
                float mx = ma.x + mb.x + mc.x + md.x;
                float my = ma.y + mb.y + mc.y + md.y;
                float mz = ma.z + mb.z + mc.z + md.z;
                float mw = ma.w + mb.w + mc.w + md.w;
                acc += a.x * mx + a.y * my + a.z * mz + a.w * mw;
            }
            jout[(size_t)(b0 + bl) * 63 + rem] = acc;
        }
    }
}

extern "C" void kernel_launch(void* const* d_in, const int* in_sizes, int n_in,
                              void* d_out, int out_size, void* d_ws, size_t ws_size,
                              hipStream_t stream) {
    const float* theta = (const float*)d_in[1];
    const float* wrist = (const float*)d_in[2];
    const float* vtpl  = (const float*)d_in[3];
    const float* jreg  = (const float*)d_in[4];
    const float* hc    = (const float*)d_in[5];
    const float* hm    = (const float*)d_in[6];
    const float* wts   = (const float*)d_in[7];
    int B = in_sizes[1] / 45;  // 4096

    float* ws    = (float*)d_ws;
    float* wsA   = ws;                         // B*192
    float* euler = ws + (size_t)B * 192;       // B*45
    float* Mpart = euler + (size_t)B * 45;     // 4*1392
    float* verts = (float*)d_out;
    float* jout  = verts + (size_t)B * NV * 3;

    int nEuler = (B * 45 + 383) / 384;
    prep_kernel<<<nEuler + 4, 384, 0, stream>>>(theta, hc, hm, vtpl, jreg, wts,
                                                euler, Mpart, B);
    fk_kernel<<<(B * 5 + 255) / 256, 256, 0, stream>>>(wrist, euler, Mpart, wsA, B * 5);
    verts_joints_kernel<<<(B / NB) * 3, 256, 0, stream>>>(wsA, Mpart, wts, vtpl, verts, jout);
}

// Round 6
// 101.187 us; speedup vs baseline: 1.3396x; 1.3396x over previous
//
#include <hip/hip_runtime.h>

#define NV 1084
#define NB 8       // batches per verts block
#define NPART 64   // precompute partials

// ws layout (floats):
//  [0, B*192)            A_rel [B][16][12]
//  next B*45             euler_pose [B][45]
//  next NPART*1392       Mpart[p]: M[21][16][4] (1344) + jt[48]
//  next 1344             Mfinal [21][16][4]

__device__ inline void rodrigues9(float x, float y, float z, float R[9]) {
    float n2 = x * x + y * y + z * z + 1e-8f;
    float angle = sqrtf(n2);
    float inv = 1.0f / angle;
    float ax = x * inv, ay = y * inv, az = z * inv;
    float c = cosf(angle), s = sinf(angle);
    float C = 1.0f - c;
    R[0] = 1.0f - C * (ay * ay + az * az);
    R[1] = -s * az + C * ax * ay;
    R[2] = s * ay + C * ax * az;
    R[3] = s * az + C * ax * ay;
    R[4] = 1.0f - C * (ax * ax + az * az);
    R[5] = -s * ax + C * ay * az;
    R[6] = -s * ay + C * ax * az;
    R[7] = s * ax + C * ay * az;
    R[8] = 1.0f - C * (ax * ax + ay * ay);
}

// K1: blocks [0, nEuler): euler_pose. blocks [nEuler, nEuler+NPART): partial
// M/jt over 17 vertices each (64*17 = 1088 >= 1084). No atomics, no memset.
__global__ __launch_bounds__(384) void prep_kernel(
    const float* __restrict__ theta, const float* __restrict__ hc,
    const float* __restrict__ hm, const float* __restrict__ vt,
    const float* __restrict__ jreg, const float* __restrict__ wts,
    float* __restrict__ euler, float* __restrict__ Mpart, int B) {
    int blk = blockIdx.x;
    int t = threadIdx.x;
    int nEuler = (B * 45 + 383) / 384;
    if (blk < nEuler) {
        int i = blk * 384 + t;
        if (i < B * 45) {
            int b = i / 45, col = i - b * 45;
            const float* th = theta + (size_t)b * 45;
            float acc = hm[col];
#pragma unroll
            for (int k = 0; k < 45; ++k) acc += th[k] * hc[k * 45 + col];
            euler[i] = acc;
        }
    } else {
        int p = blk - nEuler;           // 0..NPART-1
        int v0 = p * 17, v1 = min(v0 + 17, NV);
        float* mp = Mpart + (size_t)p * 1392;
        if (t < 336) {
            int j = t >> 4, k = t & 15;
            float m0 = 0.f, m1 = 0.f, m2 = 0.f, s = 0.f;
            for (int v = v0; v < v1; ++v) {
                float jw = jreg[v * 21 + j] * wts[v * 16 + k];
                m0 += jw * vt[v * 3 + 0];
                m1 += jw * vt[v * 3 + 1];
                m2 += jw * vt[v * 3 + 2];
                s += jw;
            }
            mp[t * 4 + 0] = m0;
            mp[t * 4 + 1] = m1;
            mp[t * 4 + 2] = m2;
            mp[t * 4 + 3] = s;
        } else if (t < 384) {           // 48 jt entries
            int o = t - 336;
            int j = o / 3, c = o - j * 3;   // j < 16
            float acc = 0.f;
            for (int v = v0; v < v1; ++v) acc += vt[v * 3 + c] * jreg[v * 21 + j];
            mp[1344 + o] = acc;
        }
    }
}

// K2: blocks [0, nFK): FK per (batch, chain-role). Blocks [nFK, nFK+2):
// reduce the NPART M-partials into Mfinal (for K3's joints chunk).
__global__ __launch_bounds__(256) void fk_kernel(
    const float* __restrict__ wrist, const float* __restrict__ euler,
    const float* __restrict__ Mpart, float* __restrict__ wsA,
    float* __restrict__ Mfinal, int total, int nFK) {
    int blk = blockIdx.x;
    int t = threadIdx.x;
    if (blk >= nFK) {
        int o = (blk - nFK) * 512 + t;      // two blocks on 256 threads: o in [0,1024) — wait, need 1344
        // cover 1344 outputs with 2 blocks x 256 threads x 3 strided iters
        for (int q = (blk - nFK) * 256 + t; q < 1344; q += 512) {
            float acc = 0.f;
#pragma unroll
            for (int p = 0; p < NPART; ++p) acc += Mpart[p * 1392 + q];
            Mfinal[q] = acc;
        }
        (void)o;
        return;
    }
    __shared__ float sj[48];
    if (t < 48) {
        float acc = 0.f;
#pragma unroll
        for (int p = 0; p < NPART; ++p) acc += Mpart[p * 1392 + 1344 + t];
        sj[t] = acc;
    }
    __syncthreads();
    int idx = blk * 256 + t;
    if (idx >= total) return;  // total = B*5
    int b = idx / 5, r = idx - b * 5;

    float R[9];
    rodrigues9(wrist[b * 3 + 0], wrist[b * 3 + 1], wrist[b * 3 + 2], R);
    float J0x = sj[0], J0y = sj[1], J0z = sj[2];
    float Ap[12];
    Ap[0] = R[0]; Ap[1] = R[1]; Ap[2] = R[2]; Ap[3] = J0x;
    Ap[4] = R[3]; Ap[5] = R[4]; Ap[6] = R[5]; Ap[7] = J0y;
    Ap[8] = R[6]; Ap[9] = R[7]; Ap[10] = R[8]; Ap[11] = J0z;
    float* out = wsA + (size_t)b * 192;
    if (r == 0) {
#pragma unroll
        for (int row = 0; row < 3; ++row) {
            out[row * 4 + 0] = Ap[row * 4 + 0];
            out[row * 4 + 1] = Ap[row * 4 + 1];
            out[row * 4 + 2] = Ap[row * 4 + 2];
            out[row * 4 + 3] = Ap[row * 4 + 3] -
                (Ap[row * 4 + 0] * J0x + Ap[row * 4 + 1] * J0y + Ap[row * 4 + 2] * J0z);
        }
    }
    float px = J0x, py = J0y, pz = J0z;
    const float* eb = euler + (size_t)b * 45 + 9 * r;
#pragma unroll
    for (int s = 0; s < 3; ++s) {
        int i = r * 3 + s + 1;
        rodrigues9(eb[3 * s + 0], eb[3 * s + 1], eb[3 * s + 2], R);
        float jx = sj[i * 3 + 0], jy = sj[i * 3 + 1], jz = sj[i * 3 + 2];
        float tx = jx - px, ty = jy - py, tz = jz - pz;
        float An[12];
#pragma unroll
        for (int row = 0; row < 3; ++row) {
            An[row * 4 + 0] = Ap[row * 4 + 0] * R[0] + Ap[row * 4 + 1] * R[3] + Ap[row * 4 + 2] * R[6];
            An[row * 4 + 1] = Ap[row * 4 + 0] * R[1] + Ap[row * 4 + 1] * R[4] + Ap[row * 4 + 2] * R[7];
            An[row * 4 + 2] = Ap[row * 4 + 0] * R[2] + Ap[row * 4 + 1] * R[5] + Ap[row * 4 + 2] * R[8];
            An[row * 4 + 3] = Ap[row * 4 + 3] + Ap[row * 4 + 0] * tx + Ap[row * 4 + 1] * ty + Ap[row * 4 + 2] * tz;
        }
        float* oi = out + i * 12;
#pragma unroll
        for (int row = 0; row < 3; ++row) {
            oi[row * 4 + 0] = An[row * 4 + 0];
            oi[row * 4 + 1] = An[row * 4 + 1];
            oi[row * 4 + 2] = An[row * 4 + 2];
            oi[row * 4 + 3] = An[row * 4 + 3] -
                (An[row * 4 + 0] * jx + An[row * 4 + 1] * jy + An[row * 4 + 2] * jz);
        }
#pragma unroll
        for (int q = 0; q < 12; ++q) Ap[q] = An[q];
        px = jx; py = jy; pz = jz;
    }
}

#define BLEND16(T, w)                                                     \
    {                                                                     \
        _Pragma("unroll")                                                 \
        for (int q = 0; q < 12; ++q) T[q] = w[0] * A[q];                  \
        _Pragma("unroll")                                                 \
        for (int k = 1; k < 16; ++k) {                                    \
            float wk = w[k];                                              \
            _Pragma("unroll")                                             \
            for (int q = 0; q < 12; ++q) T[q] += wk * A[k * 12 + q];      \
        }                                                                 \
    }

__device__ inline void load_w16(const float* __restrict__ wts, int v, float* w) {
    const float4* wp = (const float4*)&wts[v * 16];
    float4 q0 = wp[0], q1 = wp[1], q2 = wp[2], q3 = wp[3];
    w[0] = q0.x; w[1] = q0.y; w[2] = q0.z; w[3] = q0.w;
    w[4] = q1.x; w[5] = q1.y; w[6] = q1.z; w[7] = q1.w;
    w[8] = q2.x; w[9] = q2.y; w[10] = q2.z; w[11] = q2.w;
    w[12] = q3.x; w[13] = q3.y; w[14] = q3.z; w[15] = q3.w;
}

// K3: grid = (B/NB)*3. chunk 0/1: 512 verts each (VPT=2). chunk 2: 60-vert tail + joints.
// A is wave-uniform -> SGPR s_loads; no LDS.
__global__ __launch_bounds__(256) void verts_joints_kernel(
    const float* __restrict__ wsA, const float* __restrict__ Mfinal,
    const float* __restrict__ wts, const float* __restrict__ vtpl,
    float* __restrict__ verts, float* __restrict__ jout) {
    int bid = blockIdx.x;
    int bg = bid / 3, chunk = bid - bg * 3;
    int t = threadIdx.x;
    int b0 = bg * NB;

    if (chunk < 2) {
        int v0 = chunk * 512 + t;       // v0 and v0+256, both < 1024 <= NV
        int v1 = v0 + 256;
        float w0[16], w1[16];
        load_w16(wts, v0, w0);
        load_w16(wts, v1, w1);
        float vx0 = vtpl[v0 * 3 + 0], vy0 = vtpl[v0 * 3 + 1], vz0 = vtpl[v0 * 3 + 2];
        float vx1 = vtpl[v1 * 3 + 0], vy1 = vtpl[v1 * 3 + 1], vz1 = vtpl[v1 * 3 + 2];
#pragma unroll 1
        for (int bb = 0; bb < NB; ++bb) {
            const float* A = wsA + (size_t)(b0 + bb) * 192;  // uniform -> SGPR
            float T0[12], T1[12];
            BLEND16(T0, w0)
            BLEND16(T1, w1)
            float* ob = verts + (size_t)(b0 + bb) * (NV * 3);
            float ox = T0[0] * vx0 + T0[1] * vy0 + T0[2] * vz0 + T0[3];
            float oy = T0[4] * vx0 + T0[5] * vy0 + T0[6] * vz0 + T0[7];
            float oz = T0[8] * vx0 + T0[9] * vy0 + T0[10] * vz0 + T0[11];
            ob[v0 * 3 + 0] = ox; ob[v0 * 3 + 1] = oy; ob[v0 * 3 + 2] = oz;
            ox = T1[0] * vx1 + T1[1] * vy1 + T1[2] * vz1 + T1[3];
            oy = T1[4] * vx1 + T1[5] * vy1 + T1[6] * vz1 + T1[7];
            oz = T1[8] * vx1 + T1[9] * vy1 + T1[10] * vz1 + T1[11];
            ob[v1 * 3 + 0] = ox; ob[v1 * 3 + 1] = oy; ob[v1 * 3 + 2] = oz;
        }
    } else {
        // tail verts 1024..1083 (60 lanes) + joints for these NB batches
        int v = 1024 + t;
        bool valid = (v < NV);
        float w[16];
        float vx = 0.f, vy = 0.f, vz = 0.f;
        if (valid) {
            load_w16(wts, v, w);
            vx = vtpl[v * 3 + 0]; vy = vtpl[v * 3 + 1]; vz = vtpl[v * 3 + 2];
        } else {
#pragma unroll
            for (int q = 0; q < 16; ++q) w[q] = 0.f;
        }
#pragma unroll 1
        for (int bb = 0; bb < NB; ++bb) {
            const float* A = wsA + (size_t)(b0 + bb) * 192;
            float T[12];
            BLEND16(T, w)
            if (valid) {
                float ox = T[0] * vx + T[1] * vy + T[2] * vz + T[3];
                float oy = T[4] * vx + T[5] * vy + T[6] * vz + T[7];
                float oz = T[8] * vx + T[9] * vy + T[10] * vz + T[11];
                float* o = verts + (size_t)(b0 + bb) * (NV * 3) + v * 3;
                o[0] = ox; o[1] = oy; o[2] = oz;
            }
        }
        // joints: jout[b, j, c] = sum_k sum_d M[j][k][d] * A[b][k][c*4+d]
        for (int o = t; o < NB * 63; o += 256) {
            int bl = o / 63;
            int rem = o - bl * 63;
            int j = rem / 3;
            int c = rem - j * 3;
            const float* A = wsA + (size_t)(b0 + bl) * 192 + c * 4;
            const float* Mj = Mfinal + j * 64;
            float acc = 0.f;
#pragma unroll
            for (int k = 0; k < 16; ++k) {
                float4 a = *(const float4*)&A[k * 12];
                float4 m = *(const float4*)&Mj[k * 4];
                acc += a.x * m.x + a.y * m.y + a.z * m.z + a.w * m.w;
            }
            jout[(size_t)(b0 + bl) * 63 + rem] = acc;
        }
    }
}

extern "C" void kernel_launch(void* const* d_in, const int* in_sizes, int n_in,
                              void* d_out, int out_size, void* d_ws, size_t ws_size,
                              hipStream_t stream) {
    const float* theta = (const float*)d_in[1];
    const float* wrist = (const float*)d_in[2];
    const float* vtpl  = (const float*)d_in[3];
    const float* jreg  = (const float*)d_in[4];
    const float* hc    = (const float*)d_in[5];
    const float* hm    = (const float*)d_in[6];
    const float* wts   = (const float*)d_in[7];
    int B = in_sizes[1] / 45;  // 4096

    float* ws     = (float*)d_ws;
    float* wsA    = ws;                            // B*192
    float* euler  = ws + (size_t)B * 192;          // B*45
    float* Mpart  = euler + (size_t)B * 45;        // NPART*1392
    float* Mfinal = Mpart + (size_t)NPART * 1392;  // 1344
    float* verts  = (float*)d_out;
    float* jout   = verts + (size_t)B * NV * 3;

    int nEuler = (B * 45 + 383) / 384;
    prep_kernel<<<nEuler + NPART, 384, 0, stream>>>(theta, hc, hm, vtpl, jreg, wts,
                                                    euler, Mpart, B);
    int nFK = (B * 5 + 255) / 256;
    fk_kernel<<<nFK + 2, 256, 0, stream>>>(wrist, euler, Mpart, wsA, Mfinal, B * 5, nFK);
    verts_joints_kernel<<<(B / NB) * 3, 256, 0, stream>>>(wsA, Mfinal, wts, vtpl, verts, jout);
}

// Round 7
// 61.642 us; speedup vs baseline: 2.1991x; 1.6415x over previous
//
#include <hip/hip_runtime.h>

#define NV 1084
#define NB 8       // batches per verts block
#define NPART 64   // precompute partials

// ws layout (floats):
//  [0, B*192)            A_rel [B][16][12]
//  next B*45             euler_pose [B][45]
//  next NPART*1392       Mpart[p]: M[21][16][4] (1344) + jt[48]
//  next 1344             Mfinal [21][16][4]

__device__ inline void rodrigues9(float x, float y, float z, float R[9]) {
    float n2 = x * x + y * y + z * z + 1e-8f;
    float angle = sqrtf(n2);
    float inv = 1.0f / angle;
    float ax = x * inv, ay = y * inv, az = z * inv;
    float c = cosf(angle), s = sinf(angle);
    float C = 1.0f - c;
    R[0] = 1.0f - C * (ay * ay + az * az);
    R[1] = -s * az + C * ax * ay;
    R[2] = s * ay + C * ax * az;
    R[3] = s * az + C * ax * ay;
    R[4] = 1.0f - C * (ax * ax + az * az);
    R[5] = -s * ax + C * ay * az;
    R[6] = -s * ay + C * ax * az;
    R[7] = s * ax + C * ay * az;
    R[8] = 1.0f - C * (ax * ax + ay * ay);
}

// K1: blocks [0, nEuler): euler_pose. blocks [nEuler, nEuler+NPART): partial
// M/jt over 17 vertices each (64*17 = 1088 >= 1084). No atomics, no memset.
__global__ __launch_bounds__(384) void prep_kernel(
    const float* __restrict__ theta, const float* __restrict__ hc,
    const float* __restrict__ hm, const float* __restrict__ vt,
    const float* __restrict__ jreg, const float* __restrict__ wts,
    float* __restrict__ euler, float* __restrict__ Mpart, int B) {
    int blk = blockIdx.x;
    int t = threadIdx.x;
    int nEuler = (B * 45 + 383) / 384;
    if (blk < nEuler) {
        int i = blk * 384 + t;
        if (i < B * 45) {
            int b = i / 45, col = i - b * 45;
            const float* th = theta + (size_t)b * 45;
            float acc = hm[col];
#pragma unroll
            for (int k = 0; k < 45; ++k) acc += th[k] * hc[k * 45 + col];
            euler[i] = acc;
        }
    } else {
        int p = blk - nEuler;           // 0..NPART-1
        int v0 = p * 17, v1 = min(v0 + 17, NV);
        float* mp = Mpart + (size_t)p * 1392;
        if (t < 336) {
            int j = t >> 4, k = t & 15;
            float m0 = 0.f, m1 = 0.f, m2 = 0.f, s = 0.f;
            for (int v = v0; v < v1; ++v) {
                float jw = jreg[v * 21 + j] * wts[v * 16 + k];
                m0 += jw * vt[v * 3 + 0];
                m1 += jw * vt[v * 3 + 1];
                m2 += jw * vt[v * 3 + 2];
                s += jw;
            }
            mp[t * 4 + 0] = m0;
            mp[t * 4 + 1] = m1;
            mp[t * 4 + 2] = m2;
            mp[t * 4 + 3] = s;
        } else if (t < 384) {           // 48 jt entries
            int o = t - 336;
            int j = o / 3, c = o - j * 3;   // j < 16
            float acc = 0.f;
            for (int v = v0; v < v1; ++v) acc += vt[v * 3 + c] * jreg[v * 21 + j];
            mp[1344 + o] = acc;
        }
    }
}

// K2: blocks [0, nFK): FK per (batch, chain-role). Blocks [nFK, nFK+21):
// lane-parallel reduce of the NPART M-partials into Mfinal (64 q each).
__global__ __launch_bounds__(256) void fk_kernel(
    const float* __restrict__ wrist, const float* __restrict__ euler,
    const float* __restrict__ Mpart, float* __restrict__ wsA,
    float* __restrict__ Mfinal, int total, int nFK) {
    int blk = blockIdx.x;
    int t = threadIdx.x;
    if (blk >= nFK) {
        // 21 blocks x 64 q = 1344. thread = (p-group of 16) x (64 q's): all
        // loads independent -> pipelined, ~2 memory round-trips total.
        __shared__ float sm[256];
        int q = (blk - nFK) * 64 + (t & 63);
        int pg = t >> 6;                // 0..3
        float acc = 0.f;
#pragma unroll
        for (int u = 0; u < 16; ++u) acc += Mpart[(size_t)(pg * 16 + u) * 1392 + q];
        sm[t] = acc;
        __syncthreads();
        if (pg == 0) Mfinal[q] = sm[t] + sm[t + 64] + sm[t + 128] + sm[t + 192];
        return;
    }
    // jt reduce, lane-parallel: 192 threads = 4 p-groups x 48 entries, 16
    // independent loads each, then LDS tree.
    __shared__ float sred[192];
    __shared__ float sj[48];
    if (t < 192) {
        int g = t / 48, o = t - g * 48;
        float acc = 0.f;
#pragma unroll
        for (int u = 0; u < 16; ++u)
            acc += Mpart[(size_t)(g * 16 + u) * 1392 + 1344 + o];
        sred[t] = acc;
    }
    __syncthreads();
    if (t < 48) sj[t] = sred[t] + sred[48 + t] + sred[96 + t] + sred[144 + t];
    __syncthreads();

    int idx = blk * 256 + t;
    if (idx >= total) return;  // total = B*5
    int b = idx / 5, r = idx - b * 5;

    float R[9];
    rodrigues9(wrist[b * 3 + 0], wrist[b * 3 + 1], wrist[b * 3 + 2], R);
    float J0x = sj[0], J0y = sj[1], J0z = sj[2];
    float Ap[12];
    Ap[0] = R[0]; Ap[1] = R[1]; Ap[2] = R[2]; Ap[3] = J0x;
    Ap[4] = R[3]; Ap[5] = R[4]; Ap[6] = R[5]; Ap[7] = J0y;
    Ap[8] = R[6]; Ap[9] = R[7]; Ap[10] = R[8]; Ap[11] = J0z;
    float* out = wsA + (size_t)b * 192;
    if (r == 0) {
#pragma unroll
        for (int row = 0; row < 3; ++row) {
            out[row * 4 + 0] = Ap[row * 4 + 0];
            out[row * 4 + 1] = Ap[row * 4 + 1];
            out[row * 4 + 2] = Ap[row * 4 + 2];
            out[row * 4 + 3] = Ap[row * 4 + 3] -
                (Ap[row * 4 + 0] * J0x + Ap[row * 4 + 1] * J0y + Ap[row * 4 + 2] * J0z);
        }
    }
    float px = J0x, py = J0y, pz = J0z;
    const float* eb = euler + (size_t)b * 45 + 9 * r;
#pragma unroll
    for (int s = 0; s < 3; ++s) {
        int i = r * 3 + s + 1;
        rodrigues9(eb[3 * s + 0], eb[3 * s + 1], eb[3 * s + 2], R);
        float jx = sj[i * 3 + 0], jy = sj[i * 3 + 1], jz = sj[i * 3 + 2];
        float tx = jx - px, ty = jy - py, tz = jz - pz;
        float An[12];
#pragma unroll
        for (int row = 0; row < 3; ++row) {
            An[row * 4 + 0] = Ap[row * 4 + 0] * R[0] + Ap[row * 4 + 1] * R[3] + Ap[row * 4 + 2] * R[6];
            An[row * 4 + 1] = Ap[row * 4 + 0] * R[1] + Ap[row * 4 + 1] * R[4] + Ap[row * 4 + 2] * R[7];
            An[row * 4 + 2] = Ap[row * 4 + 0] * R[2] + Ap[row * 4 + 1] * R[5] + Ap[row * 4 + 2] * R[8];
            An[row * 4 + 3] = Ap[row * 4 + 3] + Ap[row * 4 + 0] * tx + Ap[row * 4 + 1] * ty + Ap[row * 4 + 2] * tz;
        }
        float* oi = out + i * 12;
#pragma unroll
        for (int row = 0; row < 3; ++row) {
            oi[row * 4 + 0] = An[row * 4 + 0];
            oi[row * 4 + 1] = An[row * 4 + 1];
            oi[row * 4 + 2] = An[row * 4 + 2];
            oi[row * 4 + 3] = An[row * 4 + 3] -
                (An[row * 4 + 0] * jx + An[row * 4 + 1] * jy + An[row * 4 + 2] * jz);
        }
#pragma unroll
        for (int q = 0; q < 12; ++q) Ap[q] = An[q];
        px = jx; py = jy; pz = jz;
    }
}

#define BLEND16(T, w)                                                     \
    {                                                                     \
        _Pragma("unroll")                                                 \
        for (int q = 0; q < 12; ++q) T[q] = w[0] * A[q];                  \
        _Pragma("unroll")                                                 \
        for (int k = 1; k < 16; ++k) {                                    \
            float wk = w[k];                                              \
            _Pragma("unroll")                                             \
            for (int q = 0; q < 12; ++q) T[q] += wk * A[k * 12 + q];      \
        }                                                                 \
    }

__device__ inline void load_w16(const float* __restrict__ wts, int v, float* w) {
    const float4* wp = (const float4*)&wts[v * 16];
    float4 q0 = wp[0], q1 = wp[1], q2 = wp[2], q3 = wp[3];
    w[0] = q0.x; w[1] = q0.y; w[2] = q0.z; w[3] = q0.w;
    w[4] = q1.x; w[5] = q1.y; w[6] = q1.z; w[7] = q1.w;
    w[8] = q2.x; w[9] = q2.y; w[10] = q2.z; w[11] = q2.w;
    w[12] = q3.x; w[13] = q3.y; w[14] = q3.z; w[15] = q3.w;
}

// K3: grid = (B/NB)*3. chunk 0/1: 512 verts each (VPT=2). chunk 2: 60-vert tail + joints.
// A is wave-uniform -> SGPR s_loads; no LDS.
__global__ __launch_bounds__(256) void verts_joints_kernel(
    const float* __restrict__ wsA, const float* __restrict__ Mfinal,
    const float* __restrict__ wts, const float* __restrict__ vtpl,
    float* __restrict__ verts, float* __restrict__ jout) {
    int bid = blockIdx.x;
    int bg = bid / 3, chunk = bid - bg * 3;
    int t = threadIdx.x;
    int b0 = bg * NB;

    if (chunk < 2) {
        int v0 = chunk * 512 + t;       // v0 and v0+256, both < 1024 <= NV
        int v1 = v0 + 256;
        float w0[16], w1[16];
        load_w16(wts, v0, w0);
        load_w16(wts, v1, w1);
        float vx0 = vtpl[v0 * 3 + 0], vy0 = vtpl[v0 * 3 + 1], vz0 = vtpl[v0 * 3 + 2];
        float vx1 = vtpl[v1 * 3 + 0], vy1 = vtpl[v1 * 3 + 1], vz1 = vtpl[v1 * 3 + 2];
#pragma unroll 1
        for (int bb = 0; bb < NB; ++bb) {
            const float* A = wsA + (size_t)(b0 + bb) * 192;  // uniform -> SGPR
            float T0[12], T1[12];
            BLEND16(T0, w0)
            BLEND16(T1, w1)
            float* ob = verts + (size_t)(b0 + bb) * (NV * 3);
            float ox = T0[0] * vx0 + T0[1] * vy0 + T0[2] * vz0 + T0[3];
            float oy = T0[4] * vx0 + T0[5] * vy0 + T0[6] * vz0 + T0[7];
            float oz = T0[8] * vx0 + T0[9] * vy0 + T0[10] * vz0 + T0[11];
            ob[v0 * 3 + 0] = ox; ob[v0 * 3 + 1] = oy; ob[v0 * 3 + 2] = oz;
            ox = T1[0] * vx1 + T1[1] * vy1 + T1[2] * vz1 + T1[3];
            oy = T1[4] * vx1 + T1[5] * vy1 + T1[6] * vz1 + T1[7];
            oz = T1[8] * vx1 + T1[9] * vy1 + T1[10] * vz1 + T1[11];
            ob[v1 * 3 + 0] = ox; ob[v1 * 3 + 1] = oy; ob[v1 * 3 + 2] = oz;
        }
    } else {
        // tail verts 1024..1083 (60 lanes) + joints for these NB batches
        int v = 1024 + t;
        bool valid = (v < NV);
        float w[16];
        float vx = 0.f, vy = 0.f, vz = 0.f;
        if (valid) {
            load_w16(wts, v, w);
            vx = vtpl[v * 3 + 0]; vy = vtpl[v * 3 + 1]; vz = vtpl[v * 3 + 2];
        } else {
#pragma unroll
            for (int q = 0; q < 16; ++q) w[q] = 0.f;
        }
#pragma unroll 1
        for (int bb = 0; bb < NB; ++bb) {
            const float* A = wsA + (size_t)(b0 + bb) * 192;
            float T[12];
            BLEND16(T, w)
            if (valid) {
                float ox = T[0] * vx + T[1] * vy + T[2] * vz + T[3];
                float oy = T[4] * vx + T[5] * vy + T[6] * vz + T[7];
                float oz = T[8] * vx + T[9] * vy + T[10] * vz + T[11];
                float* o = verts + (size_t)(b0 + bb) * (NV * 3) + v * 3;
                o[0] = ox; o[1] = oy; o[2] = oz;
            }
        }
        // joints: jout[b, j, c] = sum_k sum_d M[j][k][d] * A[b][k][c*4+d]
        for (int o = t; o < NB * 63; o += 256) {
            int bl = o / 63;
            int rem = o - bl * 63;
            int j = rem / 3;
            int c = rem - j * 3;
            const float* A = wsA + (size_t)(b0 + bl) * 192 + c * 4;
            const float* Mj = Mfinal + j * 64;
            float acc = 0.f;
#pragma unroll
            for (int k = 0; k < 16; ++k) {
                float4 a = *(const float4*)&A[k * 12];
                float4 m = *(const float4*)&Mj[k * 4];
                acc += a.x * m.x + a.y * m.y + a.z * m.z + a.w * m.w;
            }
            jout[(size_t)(b0 + bl) * 63 + rem] = acc;
        }
    }
}

extern "C" void kernel_launch(void* const* d_in, const int* in_sizes, int n_in,
                              void* d_out, int out_size, void* d_ws, size_t ws_size,
                              hipStream_t stream) {
    const float* theta = (const float*)d_in[1];
    const float* wrist = (const float*)d_in[2];
    const float* vtpl  = (const float*)d_in[3];
    const float* jreg  = (const float*)d_in[4];
    const float* hc    = (const float*)d_in[5];
    const float* hm    = (const float*)d_in[6];
    const float* wts   = (const float*)d_in[7];
    int B = in_sizes[1] / 45;  // 4096

    float* ws     = (float*)d_ws;
    float* wsA    = ws;                            // B*192
    float* euler  = ws + (size_t)B * 192;          // B*45
    float* Mpart  = euler + (size_t)B * 45;        // NPART*1392
    float* Mfinal = Mpart + (size_t)NPART * 1392;  // 1344
    float* verts  = (float*)d_out;
    float* jout   = verts + (size_t)B * NV * 3;

    int nEuler = (B * 45 + 383) / 384;
    prep_kernel<<<nEuler + NPART, 384, 0, stream>>>(theta, hc, hm, vtpl, jreg, wts,
                                                    euler, Mpart, B);
    int nFK = (B * 5 + 255) / 256;
    fk_kernel<<<nFK + 21, 256, 0, stream>>>(wrist, euler, Mpart, wsA, Mfinal, B * 5, nFK);
    verts_joints_kernel<<<(B / NB) * 3, 256, 0, stream>>>(wsA, Mfinal, wts, vtpl, verts, jout);
}